// Round 1
// 305.238 us; speedup vs baseline: 1.0003x; 1.0003x over previous
//
#include <hip/hip_runtime.h>
#include <hip/hip_bf16.h>

typedef unsigned short ushort_t;
typedef __bf16 bf16x8 __attribute__((ext_vector_type(8)));
typedef float f32x4 __attribute__((ext_vector_type(4)));
typedef float f32x8 __attribute__((ext_vector_type(8)));

#define NTOK 1032
#define NROWS 8256       // B*N = 8*1032
#define DIMC 1024
#define QKV_ELEMS 8454144  // 8*16*1032*64 elements per tensor
#define XE 8454144         // X elements (8256*1024)
#define QWE 3145728        // qkv_w elements (3072*1024)
#define OWE 1048576        // out_w elements (1024*1024)

__device__ __forceinline__ float bf2f(ushort_t u) {
    union { unsigned int i; float f; } v; v.i = ((unsigned int)u) << 16; return v.f;
}
__device__ __forceinline__ ushort_t f2bf(float f) {
    union { float f; unsigned int i; } v; v.f = f;
    unsigned int r = v.i + 0x7fffu + ((v.i >> 16) & 1u);
    return (ushort_t)(r >> 16);
}
__device__ __forceinline__ bf16x8 cvt8(const float* p) {
    const float4 a = *(const float4*)p;
    const float4 b = *(const float4*)(p + 4);
    bf16x8 r;
    r[0] = (__bf16)a.x; r[1] = (__bf16)a.y; r[2] = (__bf16)a.z; r[3] = (__bf16)a.w;
    r[4] = (__bf16)b.x; r[5] = (__bf16)b.y; r[6] = (__bf16)b.z; r[7] = (__bf16)b.w;
    return r;
}
__device__ __forceinline__ void load_lds16(const ushort_t* g, ushort_t* l) {
    __builtin_amdgcn_global_load_lds(
        (const __attribute__((address_space(1))) unsigned int*)g,
        (__attribute__((address_space(3))) unsigned int*)l, 16, 0, 0);
}

// ---------------------------------------------------------------------------
// fp32 -> bf16 pre-conversion of X, qkv_w, out_w (RNE).
// ---------------------------------------------------------------------------
__global__ __launch_bounds__(256) void cvt_kernel(
    const float* __restrict__ X, const float* __restrict__ Wq,
    const float* __restrict__ Wo,
    ushort_t* __restrict__ Xb, ushort_t* __restrict__ Wqb,
    ushort_t* __restrict__ Wob)
{
    const long i8 = ((long)blockIdx.x * 256 + threadIdx.x) * 8;
    const float* src;
    ushort_t* dst;
    long off;
    if (i8 < XE)            { src = X;  dst = Xb;  off = i8; }
    else if (i8 < XE + QWE) { src = Wq; dst = Wqb; off = i8 - XE; }
    else                    { src = Wo; dst = Wob; off = i8 - XE - QWE; }
    *(bf16x8*)(dst + off) = cvt8(src + off);
}

// ---------------------------------------------------------------------------
// NEW: 256x256 deep-pipelined QKV GEMM (T2+T3+T4+T5).
//   8 waves (2M x 4N), per-wave 128x64 C. BK=64, 2 LDS buffers (128 KiB).
//   4 phases per K-tile: phase p computes m-quadrant p (mf=2p,2p+1) x all nf
//   x full BK = 16 MFMA, wrapped in s_setprio(1).
//   B frags for the whole tile are read in phase 0 -> B(cur) dead after the
//   p0 barrier; A quarters die per-phase. Staging schedule (region-safe):
//     p0: A-second-half of tile t+1 -> other buffer (2 loads)
//     p1: B of tile t+2             -> current buffer (4 loads)  [B dead]
//     p2: A-first-half of tile t+2  -> current buffer (2 loads)  [q0,q1 dead]
//   Tile boundary: s_waitcnt vmcnt(6) (= tile t+1 complete, t+2's 6 loads
//   still in flight -> never a full drain until the last 2 tiles) + barrier.
//   Explicit lgkmcnt(0) BEFORE each barrier makes region-death block-wide.
//   LDS k-chunk XOR swizzle (chunk ^= row&7) applied on the GLOBAL source
//   (linear global_load_lds dest) and on the ds_read address: each of the 8
//   16B bank-groups gets exactly 8 lanes per ds_read_b128 -> balanced.
// ---------------------------------------------------------------------------
__global__ __launch_bounds__(512, 2) void gemm256_kernel(
    const ushort_t* __restrict__ A, const ushort_t* __restrict__ W,
    ushort_t* __restrict__ QKV)
{
    __shared__ __align__(16) ushort_t A_lds[2 * 16384];   // 2 buf x 256 x 64
    __shared__ __align__(16) ushort_t B_lds[2 * 16384];

    const int tid  = threadIdx.x;
    const int wave = tid >> 6, lane = tid & 63;
    const int wr = wave >> 2, wc = wave & 3;        // 2 x 4 wave grid
    const int fr = lane & 15, quad = lane >> 4;
    const int m0 = blockIdx.y * 256;
    const int n0 = blockIdx.x * 256;
    const bool swap = (blockIdx.x < 8);             // Q/K blocks swapped

    // ---- staging offsets: slot s = ld*512+tid; row=s>>3, chunk=s&7;
    //      global k-chunk = (s&7) ^ (row&7)  (involution swizzle) ----
    int aoff[4], boff[4];
    #pragma unroll
    for (int ld = 0; ld < 4; ++ld) {
        const int s   = ld * 512 + tid;
        const int row = s >> 3;
        const int kc  = ((s & 7) ^ (row & 7)) * 8;
        int ar = m0 + row; if (ar > NROWS - 1) ar = NROWS - 1;
        aoff[ld] = ar * DIMC + kc;
        boff[ld] = (n0 + row) * DIMC + kc;          // n0+255 <= 3071, in-bounds
    }

    // ---- fragment read offsets (swizzled chunk, constant per lane) ----
    const int ck0 = (quad ^ (fr & 7)) * 8;          // k-sub 0 (k 0..31)
    const int ck1 = ((quad + 4) ^ (fr & 7)) * 8;    // k-sub 1 (k 32..63)
    const int abase = (wr * 128 + fr) * 64;
    const int bbase = (wc * 64 + fr) * 64;

    f32x4 acc[8][4] = {};

#define SA(ld, t, c) load_lds16(A + aoff[ld] + (t) * 64, \
                                &A_lds[(c) * 16384 + ((ld) * 512 + tid) * 8])
#define SB(ld, t, c) load_lds16(W + boff[ld] + (t) * 64, \
                                &B_lds[(c) * 16384 + ((ld) * 512 + tid) * 8])
#define WAIT_LGKM0 asm volatile("s_waitcnt lgkmcnt(0)" ::: "memory")
#define WAIT_VM6   asm volatile("s_waitcnt vmcnt(6)"  ::: "memory")
#define WAIT_VM0   asm volatile("s_waitcnt vmcnt(0)"  ::: "memory")

    // ---- prologue: tile0 complete (8), tile1 B+A-first (6) ----
    SB(0, 0, 0); SB(1, 0, 0); SB(2, 0, 0); SB(3, 0, 0);
    SA(0, 0, 0); SA(1, 0, 0); SA(2, 0, 0); SA(3, 0, 0);
    SB(0, 1, 1); SB(1, 1, 1); SB(2, 1, 1); SB(3, 1, 1);
    SA(0, 1, 1); SA(2, 1, 1);               // ld0,ld2 = rows 0-63 & 128-191
    WAIT_VM6;                               // tile0 done; tile1's 6 in flight
    __builtin_amdgcn_s_barrier();

    for (int t = 0; t < 16; ++t) {
        const int c = t & 1, o = c ^ 1;
        const int cb = c * 16384;
        bf16x8 bfrag[4][2];
        #pragma unroll
        for (int p = 0; p < 4; ++p) {
            bf16x8 af[2][2];
            #pragma unroll
            for (int mfi = 0; mfi < 2; ++mfi) {
                af[mfi][0] = *(const bf16x8*)&A_lds[cb + abase + (p * 2 + mfi) * 1024 + ck0];
                af[mfi][1] = *(const bf16x8*)&A_lds[cb + abase + (p * 2 + mfi) * 1024 + ck1];
            }
            if (p == 0) {
                #pragma unroll
                for (int nf = 0; nf < 4; ++nf) {
                    bfrag[nf][0] = *(const bf16x8*)&B_lds[cb + bbase + nf * 1024 + ck0];
                    bfrag[nf][1] = *(const bf16x8*)&B_lds[cb + bbase + nf * 1024 + ck1];
                }
                if (t + 1 < 16) { SA(1, t + 1, o); SA(3, t + 1, o); }
            } else if (p == 1) {
                if (t + 2 < 16) { SB(0, t + 2, c); SB(1, t + 2, c);
                                  SB(2, t + 2, c); SB(3, t + 2, c); }
            } else if (p == 2) {
                if (t + 2 < 16) { SA(0, t + 2, c); SA(2, t + 2, c); }
            }
            WAIT_LGKM0;                       // reads done BEFORE barrier
            if (p < 3) __builtin_amdgcn_s_barrier();
            __builtin_amdgcn_s_setprio(1);
            if (swap) {
                #pragma unroll
                for (int mfi = 0; mfi < 2; ++mfi)
                    #pragma unroll
                    for (int nf = 0; nf < 4; ++nf) {
                        acc[p * 2 + mfi][nf] = __builtin_amdgcn_mfma_f32_16x16x32_bf16(
                            bfrag[nf][0], af[mfi][0], acc[p * 2 + mfi][nf], 0, 0, 0);
                        acc[p * 2 + mfi][nf] = __builtin_amdgcn_mfma_f32_16x16x32_bf16(
                            bfrag[nf][1], af[mfi][1], acc[p * 2 + mfi][nf], 0, 0, 0);
                    }
            } else {
                #pragma unroll
                for (int mfi = 0; mfi < 2; ++mfi)
                    #pragma unroll
                    for (int nf = 0; nf < 4; ++nf) {
                        acc[p * 2 + mfi][nf] = __builtin_amdgcn_mfma_f32_16x16x32_bf16(
                            af[mfi][0], bfrag[nf][0], acc[p * 2 + mfi][nf], 0, 0, 0);
                        acc[p * 2 + mfi][nf] = __builtin_amdgcn_mfma_f32_16x16x32_bf16(
                            af[mfi][1], bfrag[nf][1], acc[p * 2 + mfi][nf], 0, 0, 0);
                    }
            }
            __builtin_amdgcn_s_setprio(0);
        }
        if (t < 14)       { WAIT_VM6; __builtin_amdgcn_s_barrier(); }
        else if (t == 14) { WAIT_VM0; __builtin_amdgcn_s_barrier(); }
    }

    // ---- epilogue ----
    const int rb = quad * 4;
    if (swap) {
        // Q/K: D[col = token m][reg = feature]; each wave-col = one head.
        const int part   = n0 >> 10;
        const int hgbase = ((n0 & 1023) + wc * 64) >> 6;
        #pragma unroll
        for (int mf = 0; mf < 8; ++mf) {
            const int m = m0 + wr * 128 + mf * 16 + fr;
            if (m < NROWS) {
                const int bb = m / NTOK, n = m - bb * NTOK;
                ushort_t* outb = QKV + (long)part * QKV_ELEMS +
                    ((long)(bb * 16 + hgbase) * NTOK + n) * 64 + rb;
                #pragma unroll
                for (int nf = 0; nf < 4; ++nf) {
                    ushort4 pk;
                    pk.x = f2bf(acc[mf][nf][0]);
                    pk.y = f2bf(acc[mf][nf][1]);
                    pk.z = f2bf(acc[mf][nf][2]);
                    pk.w = f2bf(acc[mf][nf][3]);
                    *(ushort4*)(outb + nf * 16) = pk;
                }
            }
        }
    } else {
        // V: D[col = feature][reg = token] -> Vt[bh][d][n] (dim-major)
        const int hg = ((n0 & 1023) + wc * 64) >> 6;
        #pragma unroll
        for (int nf = 0; nf < 4; ++nf) {
            const int d = nf * 16 + fr;
            #pragma unroll
            for (int mf = 0; mf < 8; ++mf) {
                const int mb = m0 + wr * 128 + mf * 16 + rb;
                if (mb < NROWS) {
                    const int bb = mb / NTOK, n = mb - bb * NTOK;
                    ushort4 pk;
                    pk.x = f2bf(acc[mf][nf][0]);
                    pk.y = f2bf(acc[mf][nf][1]);
                    pk.z = f2bf(acc[mf][nf][2]);
                    pk.w = f2bf(acc[mf][nf][3]);
                    *(ushort4*)(QKV + 2L * QKV_ELEMS +
                        ((long)((bb * 16 + hg) * 64 + d)) * NTOK + n) = pk;
                }
            }
        }
    }
#undef SA
#undef SB
#undef WAIT_LGKM0
#undef WAIT_VM6
#undef WAIT_VM0
}

// ---------------------------------------------------------------------------
// Old 128x128 GEMM, kept for MODE 1 (out-projection).
// ---------------------------------------------------------------------------
template<int MODE>
__global__ __launch_bounds__(256) void gemm_kernel(
    const ushort_t* __restrict__ A, const ushort_t* __restrict__ W,
    ushort_t* __restrict__ QKV, float* __restrict__ Out)
{
    __shared__ __align__(16) ushort_t As0[128 * 32];
    __shared__ __align__(16) ushort_t As1[128 * 32];
    __shared__ __align__(16) ushort_t Bs0[128 * 32];
    __shared__ __align__(16) ushort_t Bs1[128 * 32];
    const int tid  = threadIdx.x;
    const int wave = tid >> 6, lane = tid & 63;
    const int m0 = blockIdx.y * 128;
    const int n0 = blockIdx.x * 128;
    const bool swap = (MODE == 1) || (blockIdx.x < 16);

    f32x4 acc[4][4] = {};

    const int s0 = tid, s1 = tid + 256;
    int ar0 = m0 + (s0 >> 2); if (ar0 > NROWS - 1) ar0 = NROWS - 1;
    int ar1 = m0 + (s1 >> 2); if (ar1 > NROWS - 1) ar1 = NROWS - 1;
    const int br0 = n0 + (s0 >> 2);
    const int br1 = n0 + (s1 >> 2);
    const int kc0 = (s0 & 3) * 8, kc1 = (s1 & 3) * 8;

    const ushort_t* ga0 = A + (long)ar0 * DIMC + kc0;
    const ushort_t* ga1 = A + (long)ar1 * DIMC + kc1;
    const ushort_t* gw0 = W + (long)br0 * DIMC + kc0;
    const ushort_t* gw1 = W + (long)br1 * DIMC + kc1;
    ushort_t* la00 = &As0[s0 * 8]; ushort_t* la01 = &As1[s0 * 8];
    ushort_t* la10 = &As0[s1 * 8]; ushort_t* la11 = &As1[s1 * 8];
    ushort_t* lb00 = &Bs0[s0 * 8]; ushort_t* lb01 = &Bs1[s0 * 8];
    ushort_t* lb10 = &Bs0[s1 * 8]; ushort_t* lb11 = &Bs1[s1 * 8];

    const int wm = (wave >> 1) * 64, wn = (wave & 1) * 64;
    const int fr = lane & 15, fk = (lane >> 4) * 8;
    const int arow = (wm + fr) * 32 + fk;
    const int brow = (wn + fr) * 32 + fk;

    for (int k0 = 0; k0 < DIMC; k0 += 64) {
        load_lds16(ga0 + k0,      la00);
        load_lds16(ga0 + k0 + 32, la01);
        load_lds16(ga1 + k0,      la10);
        load_lds16(ga1 + k0 + 32, la11);
        load_lds16(gw0 + k0,      lb00);
        load_lds16(gw0 + k0 + 32, lb01);
        load_lds16(gw1 + k0,      lb10);
        load_lds16(gw1 + k0 + 32, lb11);
        __syncthreads();

        {
            bf16x8 af[4], bfr[4];
            #pragma unroll
            for (int mi = 0; mi < 4; ++mi)
                af[mi] = *(const bf16x8*)&As0[arow + mi * 16 * 32];
            #pragma unroll
            for (int ni = 0; ni < 4; ++ni)
                bfr[ni] = *(const bf16x8*)&Bs0[brow + ni * 16 * 32];
            if (swap) {
                #pragma unroll
                for (int mi = 0; mi < 4; ++mi)
                    #pragma unroll
                    for (int ni = 0; ni < 4; ++ni)
                        acc[mi][ni] = __builtin_amdgcn_mfma_f32_16x16x32_bf16(
                            bfr[ni], af[mi], acc[mi][ni], 0, 0, 0);
            } else {
                #pragma unroll
                for (int mi = 0; mi < 4; ++mi)
                    #pragma unroll
                    for (int ni = 0; ni < 4; ++ni)
                        acc[mi][ni] = __builtin_amdgcn_mfma_f32_16x16x32_bf16(
                            af[mi], bfr[ni], acc[mi][ni], 0, 0, 0);
            }
        }
        {
            bf16x8 af[4], bfr[4];
            #pragma unroll
            for (int mi = 0; mi < 4; ++mi)
                af[mi] = *(const bf16x8*)&As1[arow + mi * 16 * 32];
            #pragma unroll
            for (int ni = 0; ni < 4; ++ni)
                bfr[ni] = *(const bf16x8*)&Bs1[brow + ni * 16 * 32];
            if (swap) {
                #pragma unroll
                for (int mi = 0; mi < 4; ++mi)
                    #pragma unroll
                    for (int ni = 0; ni < 4; ++ni)
                        acc[mi][ni] = __builtin_amdgcn_mfma_f32_16x16x32_bf16(
                            bfr[ni], af[mi], acc[mi][ni], 0, 0, 0);
            } else {
                #pragma unroll
                for (int mi = 0; mi < 4; ++mi)
                    #pragma unroll
                    for (int ni = 0; ni < 4; ++ni)
                        acc[mi][ni] = __builtin_amdgcn_mfma_f32_16x16x32_bf16(
                            af[mi], bfr[ni], acc[mi][ni], 0, 0, 0);
            }
        }
        __syncthreads();
    }

    const int col = lane & 15, rb = (lane >> 4) * 4;

    if (MODE == 0 && swap) {
        const int part = n0 >> 10;
        #pragma unroll
        for (int mi = 0; mi < 4; ++mi) {
            const int m = m0 + wm + mi * 16 + col;
            if (m < NROWS) {
                const int bb = m / NTOK, n = m - bb * NTOK;
                #pragma unroll
                for (int ni = 0; ni < 4; ++ni) {
                    const int rem = (n0 & 1023) + wn + ni * 16 + rb;
                    const int hg = rem >> 6, d = rem & 63;
                    ushort4 pk;
                    pk.x = f2bf(acc[mi][ni][0]);
                    pk.y = f2bf(acc[mi][ni][1]);
                    pk.z = f2bf(acc[mi][ni][2]);
                    pk.w = f2bf(acc[mi][ni][3]);
                    *(ushort4*)(QKV + (long)part * QKV_ELEMS +
                        ((long)(bb * 16 + hg) * NTOK + n) * 64 + d) = pk;
                }
            }
        }
    } else if (MODE == 0) {
        #pragma unroll
        for (int ni = 0; ni < 4; ++ni) {
            const int o = n0 + wn + ni * 16 + col;
            const int rem = o & 1023;
            const int hg = rem >> 6, d = rem & 63;
            #pragma unroll
            for (int mi = 0; mi < 4; ++mi) {
                const int mb = m0 + wm + mi * 16 + rb;
                if (mb < NROWS) {
                    const int bb = mb / NTOK, n = mb - bb * NTOK;
                    ushort4 pk;
                    pk.x = f2bf(acc[mi][ni][0]);
                    pk.y = f2bf(acc[mi][ni][1]);
                    pk.z = f2bf(acc[mi][ni][2]);
                    pk.w = f2bf(acc[mi][ni][3]);
                    *(ushort4*)(QKV + 2L * QKV_ELEMS +
                        ((long)((bb * 16 + hg) * 64 + d)) * NTOK + n) = pk;
                }
            }
        }
    } else {
        #pragma unroll
        for (int mi = 0; mi < 4; ++mi) {
            const int m = m0 + wm + mi * 16 + col;
            if (m < NROWS) {
                #pragma unroll
                for (int ni = 0; ni < 4; ++ni) {
                    const int o = n0 + wn + ni * 16 + rb;
                    float4 pk;
                    pk.x = acc[mi][ni][0];
                    pk.y = acc[mi][ni][1];
                    pk.z = acc[mi][ni][2];
                    pk.w = acc[mi][ni][3];
                    *(float4*)(Out + (long)m * DIMC + o) = pk;
                }
            }
        }
    }
}

// ---------------------------------------------------------------------------
// RMSNorm + RoPE, one THREAD per head-token vector.
// ---------------------------------------------------------------------------
__global__ __launch_bounds__(256) void rope_kernel(
    ushort_t* __restrict__ Qb, ushort_t* __restrict__ Kb,
    const float* __restrict__ cosb, const float* __restrict__ sinb,
    const float* __restrict__ wq, const float* __restrict__ wk)
{
    __shared__ float wsh[64];
    const int idx = blockIdx.x * 256 + threadIdx.x;
    const int tensor = (idx >= 132096) ? 1 : 0;
    const int r = idx - tensor * 132096;
    const int n = r % NTOK;
    if (threadIdx.x < 64) wsh[threadIdx.x] = (tensor ? wk : wq)[threadIdx.x];
    __syncthreads();

    ushort_t* base = (tensor ? Kb : Qb) + (long)r * 64;
    bf16x8 xc[8];
    #pragma unroll
    for (int c = 0; c < 8; ++c) xc[c] = *(const bf16x8*)(base + c * 8);

    float ss = 0.f;
    #pragma unroll
    for (int c = 0; c < 8; ++c) {
        const f32x8 xf = __builtin_convertvector(xc[c], f32x8);
        #pragma unroll
        for (int e = 0; e < 8; ++e) ss += xf[e] * xf[e];
    }
    const float rms = rsqrtf(ss * (1.0f / 64.0f) + 1e-6f);

    const float* cosp = cosb + n * 64;
    const float* sinp = sinb + n * 64;
    #pragma unroll
    for (int c = 0; c < 8; ++c) {
        const f32x8 xf = __builtin_convertvector(xc[c], f32x8);
        const f32x8 pf = __builtin_convertvector(xc[c ^ 4], f32x8);
        const float sgn = (c < 4) ? -1.f : 1.f;
        bf16x8 o8;
        #pragma unroll
        for (int e = 0; e < 8; ++e) {
            const float xn  = xf[e] * rms * wsh[c * 8 + e];
            const float rot = sgn * pf[e] * rms * wsh[(c ^ 4) * 8 + e];
            o8[e] = (__bf16)(xn * cosp[c * 8 + e] + rot * sinp[c * 8 + e]);
        }
        *(bf16x8*)(base + c * 8) = o8;
    }
}

// ---------------------------------------------------------------------------
// Merged attention (unchanged).
// ---------------------------------------------------------------------------
__global__ __launch_bounds__(256) void attn_kernel(
    const ushort_t* __restrict__ Qb, const ushort_t* __restrict__ Kb,
    const ushort_t* __restrict__ Vt, ushort_t* __restrict__ AO)
{
    __shared__ __align__(16) ushort_t KP_s[256 * 72];

    const int tid = threadIdx.x;
    const int wave = tid >> 6, lane = tid & 63;
    const int m_ = lane & 15, quad = lane >> 4;
    const int nb = wave * 64;
    const int d0 = wave * 16;

    bf16x8 ones;
    #pragma unroll
    for (int e = 0; e < 8; ++e) ones[e] = (__bf16)1.0f;

    if (blockIdx.x >= 128) {
        const int blk = blockIdx.x - 128;
        const int bh = blk & 127, qr = blk >> 7;
        const int b = bh >> 4, h = bh & 15;

        int r0 = qr - 3; if (r0 < 0) r0 = 0;
        int r1 = qr + 3; if (r1 > 31) r1 = 31;
        const int limit = 8 + (r1 - r0 + 1) * 32;

        const ushort_t* Qg  = Qb + ((long)bh * NTOK + 8 + qr * 32) * 64;
        const ushort_t* Kg  = Kb + (long)bh * NTOK * 64;
        const ushort_t* Vtg = Vt + (long)bh * 64 * NTOK;

        bf16x8 af[2][2];
        #pragma unroll
        for (int mt = 0; mt < 2; ++mt)
            #pragma unroll
            for (int ks = 0; ks < 2; ++ks)
                af[mt][ks] = *(const bf16x8*)(Qg + (mt * 16 + m_) * 64 + ks * 32 + quad * 8);

        bf16x8 bv[8];
        #pragma unroll
        for (int ks = 0; ks < 8; ++ks) {
            const int slot0 = ks * 32 + quad * 8;
            int tok0;
            if (slot0 >= limit) tok0 = 0;
            else if (slot0 < 8) tok0 = slot0;
            else tok0 = 8 + r0 * 32 + (slot0 - 8);
            bv[ks] = *(const bf16x8*)(Vtg + (long)(d0 + m_) * NTOK + tok0);
        }

        for (int c = tid; c < limit * 8; c += 256) {
            const int slot = c >> 3, c8 = (c & 7) * 8;
            const int tok = slot + (slot >= 8 ? r0 * 32 : 0);
            *(bf16x8*)&KP_s[slot * 72 + c8] = *(const bf16x8*)(Kg + (long)tok * 64 + c8);
        }
        __syncthreads();

        bf16x8 bfr[4][2];
        #pragma unroll
        for (int nt = 0; nt < 4; ++nt)
            #pragma unroll
            for (int ks = 0; ks < 2; ++ks)
                bfr[nt][ks] = *(const bf16x8*)&KP_s[(nb + nt * 16 + m_) * 72 + ks * 32 + quad * 8];

        f32x4 sacc[2][4] = {};
        #pragma unroll
        for (int mt = 0; mt < 2; ++mt)
            #pragma unroll
            for (int nt = 0; nt < 4; ++nt) {
                sacc[mt][nt] = __builtin_amdgcn_mfma_f32_16x16x32_bf16(
                    af[mt][0], bfr[nt][0], sacc[mt][nt], 0, 0, 0);
                sacc[mt][nt] = __builtin_amdgcn_mfma_f32_16x16x32_bf16(
                    af[mt][1], bfr[nt][1], sacc[mt][nt], 0, 0, 0);
            }
        __syncthreads();

        #pragma unroll
        for (int mt = 0; mt < 2; ++mt)
            #pragma unroll
            for (int nt = 0; nt < 4; ++nt) {
                const int slot = nb + nt * 16 + m_;
                const int kc = (slot - 8) & 31;
                #pragma unroll
                for (int reg = 0; reg < 4; ++reg) {
                    const int qm = mt * 16 + quad * 4 + reg;
                    const bool val = (slot < 8) ||
                        ((slot < limit) && ((unsigned)(kc - qm + 3) <= 6u));
                    const float p = val ? __expf(sacc[mt][nt][reg] * 0.125f) : 0.f;
                    KP_s[qm * 280 + slot] = f2bf(p);
                }
            }
        __syncthreads();

        f32x4 oacc[2] = {}, lacc[2] = {};
        #pragma unroll
        for (int ks = 0; ks < 8; ++ks) {
            #pragma unroll
            for (int mt = 0; mt < 2; ++mt) {
                const bf16x8 ap = *(const bf16x8*)&KP_s[(mt * 16 + m_) * 280 + ks * 32 + quad * 8];
                oacc[mt] = __builtin_amdgcn_mfma_f32_16x16x32_bf16(ap, bv[ks], oacc[mt], 0, 0, 0);
                lacc[mt] = __builtin_amdgcn_mfma_f32_16x16x32_bf16(ap, ones,   lacc[mt], 0, 0, 0);
            }
        }
        #pragma unroll
        for (int mt = 0; mt < 2; ++mt)
            #pragma unroll
            for (int reg = 0; reg < 4; ++reg) {
                const int qm = mt * 16 + quad * 4 + reg;
                const int tok = 8 + qr * 32 + qm;
                AO[((long)(b * NTOK + tok)) * DIMC + h * 64 + d0 + m_] =
                    f2bf(oacc[mt][reg] / lacc[mt][reg]);
            }
    } else {
        const int bh = blockIdx.x;
        const int b = bh >> 4, h = bh & 15;
        const ushort_t* Kg  = Kb + (long)bh * NTOK * 64;
        const ushort_t* Vtg = Vt + (long)bh * 64 * NTOK;

        bf16x8 afs[2];
        if (m_ < 8) {
            #pragma unroll
            for (int ks = 0; ks < 2; ++ks)
                afs[ks] = *(const bf16x8*)(Qb + ((long)bh * NTOK + m_) * 64 + ks * 32 + quad * 8);
        } else {
            #pragma unroll
            for (int ks = 0; ks < 2; ++ks)
                #pragma unroll
                for (int e = 0; e < 8; ++e) afs[ks][e] = (__bf16)0.f;
        }

        f32x4 oacc = {}, lacc = {};
        for (int ch = 0; ch < 5; ++ch) {
            const int tok0 = ch * 256;
            const int limit = (NTOK - tok0 < 256) ? (NTOK - tok0) : 256;

            bf16x8 bv[8];
            #pragma unroll
            for (int ks = 0; ks < 8; ++ks) {
                const int slot0 = ks * 32 + quad * 8;
                const int tok = tok0 + ((slot0 < limit) ? slot0 : 0);
                bv[ks] = *(const bf16x8*)(Vtg + (long)(d0 + m_) * NTOK + tok);
            }

            __syncthreads();
            for (int c = tid; c < limit * 8; c += 256) {
                const int slot = c >> 3, c8 = (c & 7) * 8;
                *(bf16x8*)&KP_s[slot * 72 + c8] =
                    *(const bf16x8*)(Kg + (long)(tok0 + slot) * 64 + c8);
            }
            __syncthreads();

            bf16x8 bfr[4][2];
            #pragma unroll
            for (int nt = 0; nt < 4; ++nt)
                #pragma unroll
                for (int ks = 0; ks < 2; ++ks)
                    bfr[nt][ks] = *(const bf16x8*)&KP_s[(nb + nt * 16 + m_) * 72 + ks * 32 + quad * 8];
            f32x4 sacc[4] = {};
            #pragma unroll
            for (int nt = 0; nt < 4; ++nt) {
                sacc[nt] = __builtin_amdgcn_mfma_f32_16x16x32_bf16(afs[0], bfr[nt][0], sacc[nt], 0, 0, 0);
                sacc[nt] = __builtin_amdgcn_mfma_f32_16x16x32_bf16(afs[1], bfr[nt][1], sacc[nt], 0, 0, 0);
            }
            __syncthreads();

            #pragma unroll
            for (int nt = 0; nt < 4; ++nt) {
                const int slot = nb + nt * 16 + m_;
                const bool val = (slot < limit);
                #pragma unroll
                for (int reg = 0; reg < 4; ++reg) {
                    const int qm = quad * 4 + reg;
                    const float p = val ? __expf(sacc[nt][reg] * 0.125f) : 0.f;
                    KP_s[qm * 280 + slot] = f2bf(p);
                }
            }
            __syncthreads();

            #pragma unroll
            for (int ks = 0; ks < 8; ++ks) {
                const bf16x8 ap = *(const bf16x8*)&KP_s[m_ * 280 + ks * 32 + quad * 8];
                oacc = __builtin_amdgcn_mfma_f32_16x16x32_bf16(ap, bv[ks], oacc, 0, 0, 0);
                lacc = __builtin_amdgcn_mfma_f32_16x16x32_bf16(ap, ones,   lacc, 0, 0, 0);
            }
        }

        #pragma unroll
        for (int reg = 0; reg < 4; ++reg) {
            const int qm = quad * 4 + reg;
            if (qm < 8) {
                AO[((long)(b * NTOK + qm)) * DIMC + h * 64 + d0 + m_] =
                    f2bf(oacc[reg] / lacc[reg]);
            }
        }
    }
}

extern "C" void kernel_launch(void* const* d_in, const int* in_sizes, int n_in,
                              void* d_out, int out_size, void* d_ws, size_t ws_size,
                              hipStream_t stream) {
    const float* X    = (const float*)d_in[0];
    const float* fc   = (const float*)d_in[1];
    const float* fs   = (const float*)d_in[2];
    const float* qkvw = (const float*)d_in[3];
    const float* outw = (const float*)d_in[4];
    const float* nqw  = (const float*)d_in[5];
    const float* nkw  = (const float*)d_in[6];

    ushort_t* Qb  = (ushort_t*)d_ws;
    ushort_t* Kb  = Qb + QKV_ELEMS;
    ushort_t* Vt  = Kb + QKV_ELEMS;
    ushort_t* AO  = Vt + QKV_ELEMS;
    ushort_t* Xb  = AO + QKV_ELEMS;
    ushort_t* Wqb = Xb + XE;
    ushort_t* Wob = Wqb + QWE;
    float* Out = (float*)d_out;

    cvt_kernel<<<6176, 256, 0, stream>>>(X, qkvw, outw, Xb, Wqb, Wob);
    gemm256_kernel<<<dim3(12, 33), 512, 0, stream>>>(Xb, Wqb, Qb);
    rope_kernel<<<1032, 256, 0, stream>>>(Qb, Kb, fc, fs, nqw, nkw);
    attn_kernel<<<4224, 256, 0, stream>>>(Qb, Kb, Vt, AO);
    gemm_kernel<1><<<dim3(8, 65), 256, 0, stream>>>(AO, Wob, nullptr, Out);
}